// Round 12
// baseline (240.241 us; speedup 1.0000x reference)
//
#include <hip/hip_runtime.h>
#include <hip/hip_bf16.h>
#include <cstddef>

// K=2048, B=4, D=5, ATOM=125, BOND=12, HID=125, OUT=40
// NOFF = [0, 2048, 10240, 43008, 175104, 699392]
// BOFF = [0, 8192, 40960, 172032, 696320]
//
// Round 12 = round 11 (barrier-free wave-autonomous) with 16 rows/wave
// (was 32) to double occupancy:
//  - leaf: LDS 32 KB/block -> 4-5 blocks/CU (was 2); mid: 16 KB -> 6 blocks.
//  - Each wave stages its contiguous region (leaf msg 8000 B; mid msg 2000 B
//    = 4 parents, bonds 768 B, child 1280 B) flat into private LDS via
//    coalesced dwordx4. No barriers anywhere.
//  - X fragments: LDS b32 gathers (conflict-free / 2-way) + RNE cvt to f16.
//  - W1 per-fragment-contiguous in ws (w1g), 1 KB coalesced dwordx4 per
//    (chunk,mt), L1/L2-hot, no W LDS. W2 frag-packed (validated mapping).
//  - Leaf output bounced via LDS -> coalesced dwordx4 stores.
// k' layout (192): [0,125) msg, [125,128) 0, [128,140) bond, [140,144) 0,
// [144,184) child, [184,192) 0. f16, RNE. Intermediates [row][40] f16.

typedef __attribute__((ext_vector_type(8))) _Float16 h8;
typedef __attribute__((ext_vector_type(4))) float f32x4;
typedef __attribute__((ext_vector_type(4))) unsigned int v4u;

static constexpr int HID = 125, OUT = 40;

__device__ __forceinline__ unsigned short f2h(float x) {
    _Float16 h = (_Float16)x;  // RNE
    return __builtin_bit_cast(unsigned short, h);
}
__device__ __forceinline__ unsigned int pkh(float a, float b) {
    return (unsigned int)f2h(a) | ((unsigned int)f2h(b) << 16);
}

// W1 packed per-fragment: (kc,mt,ln,j) -> hid = mt*16+(ln&15),
// k' = kc*32+(ln>>4)*8+j. 6*8*64*8 f16 = 48 KB.
__global__ void prep_w1g(const float* __restrict__ W1, unsigned short* __restrict__ w1g) {
    int idx = blockIdx.x * 256 + threadIdx.x;
    if (idx >= 6 * 8 * 64 * 8) return;
    int j = idx & 7, ln = (idx >> 3) & 63, mt = (idx >> 9) & 7, kc = idx >> 12;
    int hid = mt * 16 + (ln & 15);
    int kp = kc * 32 + ((ln >> 4) << 3) + j;
    int k = (kp < 125) ? kp
          : (kp >= 128 && kp < 140) ? kp - 3
          : (kp >= 144 && kp < 184) ? kp - 7 : -1;
    float v = (k >= 0 && hid < HID) ? W1[(size_t)k * HID + hid] : 0.f;
    w1g[idx] = f2h(v);
}

// W2 frag-packed (validated): fr = kt*3+qt; elem j: hid = kt*32+16*(j>>2)+
// (ln>>4)*4+(j&3); q = qt*16+(ln&15).
__global__ void prep_w2(const float* __restrict__ W2, unsigned int* __restrict__ w2f) {
    int t = threadIdx.x;
    for (int task = t; task < 12 * 64; task += 256) {
        int ln = task & 63, fr = task >> 6;
        int kt = fr / 3, qt = fr % 3;
        int q = qt * 16 + (ln & 15);
        unsigned int w[4];
#pragma unroll
        for (int jp = 0; jp < 4; jp++) {
            unsigned short e[2];
#pragma unroll
            for (int s = 0; s < 2; s++) {
                int j = jp * 2 + s;
                int hid = kt * 32 + ((j >> 2) << 4) + ((ln >> 4) << 2) + (j & 3);
                float v = (hid < HID && q < OUT) ? W2[(size_t)hid * OUT + q] : 0.f;
                e[s] = f2h(v);
            }
            w[jp] = (unsigned int)e[0] | ((unsigned int)e[1] << 16);
        }
        v4u val = {w[0], w[1], w[2], w[3]};
        ((v4u*)w2f)[fr * 64 + ln] = val;
    }
}

// ========================= leaf kernel (d=4) =========================
// 64 rows/block, 16 rows/wave.
__global__ void __launch_bounds__(256, 4)
leaf_k(const float* __restrict__ msg, const unsigned short* __restrict__ w1g,
       const unsigned int* __restrict__ w2f,
       const float* __restrict__ b1, const float* __restrict__ b2,
       unsigned short* __restrict__ outp) {
    __shared__ float Xs[4][2000];  // per-wave raw f32: 16 rows x 125

    const int tid = threadIdx.x;
    const int lane = tid & 63;
    const int wv = tid >> 6;
    const int l15 = tid & 15;
    const int l16 = (tid >> 4) & 3;
    const int row0 = blockIdx.x * 64 + wv * 16;

    // ---- stage: 8000 B contiguous, coalesced dwordx4, wave-private ----
    {
        const f32x4* src = (const f32x4*)(msg + (size_t)row0 * 125);
        f32x4* dst = (f32x4*)&Xs[wv][0];
#pragma unroll
        for (int i = 0; i < 8; i++) {
            int u = lane + i * 64;
            if (i < 7 || u < 500) dst[u] = src[u];
        }
    }

    f32x4 acc[8];
#pragma unroll
    for (int mt = 0; mt < 8; mt++) {
#pragma unroll
        for (int r = 0; r < 4; r++) {
            int h_ = mt * 16 + l16 * 4 + r;
            acc[mt][r] = (h_ < HID) ? b1[h_] : 0.f;
        }
    }

    // ---- layer 1: 4 chunks, fragments from LDS, W direct from cache ----
#pragma unroll
    for (int j = 0; j < 4; ++j) {
        const float* rp = &Xs[wv][l15 * 125];
        const int k0 = j * 32 + l16 * 8;
        float t[8];
#pragma unroll
        for (int i = 0; i < 8; i++) {
            int col = k0 + i;
            int cs = (col < 125) ? col : 0;
            float v = rp[cs];
            t[i] = (col < 125) ? v : 0.f;
        }
        v4u xv = {pkh(t[0], t[1]), pkh(t[2], t[3]), pkh(t[4], t[5]), pkh(t[6], t[7])};
        h8 xf = __builtin_bit_cast(h8, xv);
#pragma unroll
        for (int mt = 0; mt < 8; ++mt) {
            h8 wf = *(const h8*)&w1g[(size_t)((j * 8 + mt) * 64 + lane) * 8];
            acc[mt] = __builtin_amdgcn_mfma_f32_16x16x32_f16(wf, xf, acc[mt], 0, 0, 0);
        }
    }

    // ---- lrelu + layer 2 ----
#pragma unroll
    for (int mt = 0; mt < 8; mt++)
#pragma unroll
        for (int r = 0; r < 4; r++)
            acc[mt][r] = fmaxf(acc[mt][r], 0.01f * acc[mt][r]);

    float b2v[3];
#pragma unroll
    for (int qt = 0; qt < 3; qt++) {
        int q = qt * 16 + l15;
        b2v[qt] = (q < OUT) ? b2[q] : 0.f;
    }

    h8 A[4];
#pragma unroll
    for (int kt = 0; kt < 4; kt++) {
        v4u av = {pkh(acc[2 * kt][0], acc[2 * kt][1]),
                  pkh(acc[2 * kt][2], acc[2 * kt][3]),
                  pkh(acc[2 * kt + 1][0], acc[2 * kt + 1][1]),
                  pkh(acc[2 * kt + 1][2], acc[2 * kt + 1][3])};
        A[kt] = __builtin_bit_cast(h8, av);
    }

    unsigned short* s16 = (unsigned short*)&Xs[wv][0];  // bounce (reads done)
#pragma unroll
    for (int qt = 0; qt < 3; ++qt) {
        f32x4 o = {0.f, 0.f, 0.f, 0.f};
#pragma unroll
        for (int kt = 0; kt < 4; kt++) {
            v4u wvv = ((const v4u*)w2f)[(kt * 3 + qt) * 64 + lane];
            o = __builtin_amdgcn_mfma_f32_16x16x32_f16(
                A[kt], __builtin_bit_cast(h8, wvv), o, 0, 0, 0);
        }
        int q = qt * 16 + l15;
        if (q < OUT) {
#pragma unroll
            for (int r = 0; r < 4; r++) {
                int rl = l16 * 4 + r;  // local row
                float v = o[r] + b2v[qt];
                v = fmaxf(v, 0.01f * v);
                s16[rl * 40 + q] = f2h(v);
            }
        }
    }
    // coalesced store: 16 rows x 40 f16 = 1280 B = 80 x 16 B
    {
        v4u* gdst = (v4u*)(outp + (size_t)row0 * 40);
        const v4u* s4 = (const v4u*)s16;
#pragma unroll
        for (int i = 0; i < 2; i++) {
            int u = lane + i * 64;
            if (i < 1 || u < 80) gdst[u] = s4[u];
        }
    }
}

// ========================= mid/final kernel =========================
// 64 edge rows/block, 16/wave. MODE 1: f16 out; MODE 2: fp32 out (final).
template <int MODE>
__global__ void __launch_bounds__(256, 6)
mid_k(const float* __restrict__ msg, const float* __restrict__ bonds,
      const unsigned short* __restrict__ child,
      const unsigned short* __restrict__ w1g, const unsigned int* __restrict__ w2f,
      const float* __restrict__ b1, const float* __restrict__ b2,
      void* __restrict__ outp) {
    __shared__ float MS[4][500];             // 4 parents x 125 f32
    __shared__ float BS[4][192];             // 16 rows x 12 f32
    __shared__ unsigned short CS[4][640];    // 16 rows x 40 f16

    const int tid = threadIdx.x;
    const int lane = tid & 63;
    const int wv = tid >> 6;
    const int l15 = tid & 15;
    const int l16 = (tid >> 4) & 3;
    const int row0 = blockIdx.x * 64 + wv * 16;  // edge rows
    const int par0 = row0 >> 2;                  // parent rows

    // ---- stage (wave-private, contiguous, coalesced) ----
    {
        const f32x4* sm = (const f32x4*)(msg + (size_t)par0 * 125);
        f32x4* dm = (f32x4*)&MS[wv][0];
#pragma unroll
        for (int i = 0; i < 2; i++) {
            int u = lane + i * 64;
            if (i < 1 || u < 125) dm[u] = sm[u];
        }
        const f32x4* sb = (const f32x4*)(bonds + (size_t)row0 * 12);
        f32x4* db = (f32x4*)&BS[wv][0];
        if (lane < 48) db[lane] = sb[lane];
        const v4u* sc = (const v4u*)(child + (size_t)row0 * 40);
        v4u* dc = (v4u*)&CS[wv][0];
#pragma unroll
        for (int i = 0; i < 2; i++) {
            int u = lane + i * 64;
            if (i < 1 || u < 80) dc[u] = sc[u];
        }
    }

    f32x4 acc[8];
#pragma unroll
    for (int mt = 0; mt < 8; mt++) {
#pragma unroll
        for (int r = 0; r < 4; r++) {
            int h_ = mt * 16 + l16 * 4 + r;
            acc[mt][r] = (h_ < HID) ? b1[h_] : 0.f;
        }
    }

    // ---- layer 1: 6 chunks ----
#pragma unroll
    for (int j = 0; j < 6; ++j) {
        h8 xf;
        const int rl = l15;  // local edge row 0..15
        if (j < 4) {
            const float* pp = &MS[wv][(rl >> 2) * 125];
            const int k0 = j * 32 + l16 * 8;
            float t[8];
#pragma unroll
            for (int i = 0; i < 8; i++) {
                int col = k0 + i;
                int cs = (col < 125) ? col : 0;
                float v = pp[cs];
                t[i] = (col < 125) ? v : 0.f;
            }
            v4u xv = {pkh(t[0], t[1]), pkh(t[2], t[3]), pkh(t[4], t[5]), pkh(t[6], t[7])};
            xf = __builtin_bit_cast(h8, xv);
        } else if (j == 4) {
            if (l16 < 2) {
                const float* bp = &BS[wv][rl * 12];
                float t[8];
#pragma unroll
                for (int i = 0; i < 8; i++) {
                    int c = l16 * 8 + i;
                    int cs = (c < 12) ? c : 0;
                    float v = bp[cs];
                    t[i] = (c < 12) ? v : 0.f;
                }
                v4u xv = {pkh(t[0], t[1]), pkh(t[2], t[3]), pkh(t[4], t[5]), pkh(t[6], t[7])};
                xf = __builtin_bit_cast(h8, xv);
            } else {
                xf = *(const h8*)&CS[wv][rl * 40 + (l16 - 2) * 8];  // child 0..15
            }
        } else {
            if (l16 < 3) {
                xf = *(const h8*)&CS[wv][rl * 40 + 16 + l16 * 8];   // child 16..39
            } else {
                h8 z = {};
                xf = z;
            }
        }
#pragma unroll
        for (int mt = 0; mt < 8; ++mt) {
            h8 wf = *(const h8*)&w1g[(size_t)((j * 8 + mt) * 64 + lane) * 8];
            acc[mt] = __builtin_amdgcn_mfma_f32_16x16x32_f16(wf, xf, acc[mt], 0, 0, 0);
        }
    }

    // ---- lrelu + layer 2 + sibling sum ----
#pragma unroll
    for (int mt = 0; mt < 8; mt++)
#pragma unroll
        for (int r = 0; r < 4; r++)
            acc[mt][r] = fmaxf(acc[mt][r], 0.01f * acc[mt][r]);

    float b2v[3];
#pragma unroll
    for (int qt = 0; qt < 3; qt++) {
        int q = qt * 16 + l15;
        b2v[qt] = (q < OUT) ? b2[q] : 0.f;
    }
    h8 A[4];
#pragma unroll
    for (int kt = 0; kt < 4; kt++) {
        v4u av = {pkh(acc[2 * kt][0], acc[2 * kt][1]),
                  pkh(acc[2 * kt][2], acc[2 * kt][3]),
                  pkh(acc[2 * kt + 1][0], acc[2 * kt + 1][1]),
                  pkh(acc[2 * kt + 1][2], acc[2 * kt + 1][3])};
        A[kt] = __builtin_bit_cast(h8, av);
    }
#pragma unroll
    for (int qt = 0; qt < 3; ++qt) {
        f32x4 o = {0.f, 0.f, 0.f, 0.f};
#pragma unroll
        for (int kt = 0; kt < 4; kt++) {
            v4u wvv = ((const v4u*)w2f)[(kt * 3 + qt) * 64 + lane];
            o = __builtin_amdgcn_mfma_f32_16x16x32_f16(
                A[kt], __builtin_bit_cast(h8, wvv), o, 0, 0, 0);
        }
        int q = qt * 16 + l15;
        float s = 0.f;
#pragma unroll
        for (int r = 0; r < 4; r++) {
            float v = o[r] + b2v[qt];
            s += fmaxf(v, 0.01f * v);
        }
        if (q < OUT) {
            int p = par0 + l16;  // 4 parents per wave
            if (MODE == 1)
                ((unsigned short*)outp)[(size_t)p * 40 + q] = f2h(s);
            else
                ((float*)outp)[(size_t)p * 40 + q] = s;
        }
    }
}

extern "C" void kernel_launch(void* const* d_in, const int* in_sizes, int n_in,
                              void* d_out, int out_size, void* d_ws, size_t ws_size,
                              hipStream_t stream) {
    const float* node_msg = (const float*)d_in[0];
    const float* bonds = (const float*)d_in[1];
    const float* W1 = (const float*)d_in[2];
    const float* b1 = (const float*)d_in[3];
    const float* W2 = (const float*)d_in[4];
    const float* b2 = (const float*)d_in[5];
    float* out = (float*)d_out;

    char* ws = (char*)d_ws;
    unsigned short* bufA = (unsigned short*)ws;                   // 524288*40 f16
    unsigned short* bufB = (unsigned short*)(ws + 41943040);      // 131072*40 f16
    unsigned short* w1g = (unsigned short*)(ws + 52428800);       // 49152 B
    unsigned int* w2f = (unsigned int*)(ws + 52428800 + 49152);   // 12288 B

    prep_w1g<<<96, 256, 0, stream>>>(W1, w1g);
    prep_w2<<<1, 256, 0, stream>>>(W2, w2f);

    // leaf (d=4): 524288 rows -> bufA
    leaf_k<<<8192, 256, 0, stream>>>(
        node_msg + (size_t)175104 * 125, w1g, w2f, b1, b2, bufA);
    // d=3: 524288 edges -> 131072 parents -> bufB
    mid_k<1><<<8192, 256, 0, stream>>>(
        node_msg + (size_t)43008 * 125, bonds + (size_t)172032 * 12, bufA,
        w1g, w2f, b1, b2, bufB);
    // d=2: 131072 edges -> 32768 parents -> bufA
    mid_k<1><<<2048, 256, 0, stream>>>(
        node_msg + (size_t)10240 * 125, bonds + (size_t)40960 * 12, bufB,
        w1g, w2f, b1, b2, bufA);
    // d=1: 32768 edges -> 8192 parents -> bufB
    mid_k<1><<<512, 256, 0, stream>>>(
        node_msg + (size_t)2048 * 125, bonds + (size_t)8192 * 12, bufA,
        w1g, w2f, b1, b2, bufB);
    // d=0: 8192 edges -> 2048 parents -> out (fp32)
    mid_k<2><<<128, 256, 0, stream>>>(
        node_msg, bonds, bufB, w1g, w2f, b1, b2, out);
}

// Round 13
// 202.639 us; speedup vs baseline: 1.1856x; 1.1856x over previous
//
#include <hip/hip_runtime.h>
#include <hip/hip_bf16.h>
#include <cstddef>

// K=2048, B=4, D=5, ATOM=125, BOND=12, HID=125, OUT=40
// NOFF = [0, 2048, 10240, 43008, 175104, 699392]
// BOFF = [0, 8192, 40960, 172032, 696320]
//
// Round 13 = round 11 (202 us best: barrier-free wave-autonomous, 32
// rows/wave) with the leaf kernel's staging restructured:
//  - leaf: column-slice (32 rows x 32 cols f32) double-buffered staging via
//    coalesced dword loads (2 rows x 32 lanes per instr -> 2x128B runs;
//    alignment-safe for the 500B row stride). Slice rows padded to 36 f32
//    (144 B: 16B-aligned b128 frag reads, 4r bank spread = 2-way = free).
//    Pipeline: issue(j+1) -> MFMA(j) -> ds_write(j+1); wave-private, no
//    barriers. LDS 64 KB -> 36.9 KB/block => 3 blocks/CU (12 waves/CU).
//  - mid_k, prep kernels, frag mappings, k' layout: r11 VERBATIM.
// k' layout (192): [0,125) msg, [125,128) 0, [128,140) bond, [140,144) 0,
// [144,184) child, [184,192) 0. f16, RNE. Intermediates [row][40] f16.

typedef __attribute__((ext_vector_type(8))) _Float16 h8;
typedef __attribute__((ext_vector_type(4))) float f32x4;
typedef __attribute__((ext_vector_type(4))) unsigned int v4u;

static constexpr int HID = 125, OUT = 40;

__device__ __forceinline__ unsigned short f2h(float x) {
    _Float16 h = (_Float16)x;  // RNE
    return __builtin_bit_cast(unsigned short, h);
}
__device__ __forceinline__ unsigned int pkh(float a, float b) {
    return (unsigned int)f2h(a) | ((unsigned int)f2h(b) << 16);
}

// W1 packed per-fragment: (kc,mt,ln,j) -> hid = mt*16+(ln&15),
// k' = kc*32+(ln>>4)*8+j. 6*8*64*8 f16 = 48 KB.
__global__ void prep_w1g(const float* __restrict__ W1, unsigned short* __restrict__ w1g) {
    int idx = blockIdx.x * 256 + threadIdx.x;
    if (idx >= 6 * 8 * 64 * 8) return;
    int j = idx & 7, ln = (idx >> 3) & 63, mt = (idx >> 9) & 7, kc = idx >> 12;
    int hid = mt * 16 + (ln & 15);
    int kp = kc * 32 + ((ln >> 4) << 3) + j;
    int k = (kp < 125) ? kp
          : (kp >= 128 && kp < 140) ? kp - 3
          : (kp >= 144 && kp < 184) ? kp - 7 : -1;
    float v = (k >= 0 && hid < HID) ? W1[(size_t)k * HID + hid] : 0.f;
    w1g[idx] = f2h(v);
}

// W2 frag-packed (validated): fr = kt*3+qt; elem j: hid = kt*32+16*(j>>2)+
// (ln>>4)*4+(j&3); q = qt*16+(ln&15).
__global__ void prep_w2(const float* __restrict__ W2, unsigned int* __restrict__ w2f) {
    int t = threadIdx.x;
    for (int task = t; task < 12 * 64; task += 256) {
        int ln = task & 63, fr = task >> 6;
        int kt = fr / 3, qt = fr % 3;
        int q = qt * 16 + (ln & 15);
        unsigned int w[4];
#pragma unroll
        for (int jp = 0; jp < 4; jp++) {
            unsigned short e[2];
#pragma unroll
            for (int s = 0; s < 2; s++) {
                int j = jp * 2 + s;
                int hid = kt * 32 + ((j >> 2) << 4) + ((ln >> 4) << 2) + (j & 3);
                float v = (hid < HID && q < OUT) ? W2[(size_t)hid * OUT + q] : 0.f;
                e[s] = f2h(v);
            }
            w[jp] = (unsigned int)e[0] | ((unsigned int)e[1] << 16);
        }
        v4u val = {w[0], w[1], w[2], w[3]};
        ((v4u*)w2f)[fr * 64 + ln] = val;
    }
}

// ========================= leaf kernel (d=4) =========================
// 128 rows/block, 32 rows/wave, column-slice double-buffered staging.
__global__ void __launch_bounds__(256, 3)
leaf_k(const float* __restrict__ msg, const unsigned short* __restrict__ w1g,
       const unsigned int* __restrict__ w2f,
       const float* __restrict__ b1, const float* __restrict__ b2,
       unsigned short* __restrict__ outp) {
    __shared__ float Xs[4][2][32 * 36];  // per-wave dbuf slice: 32 rows x 36 f32

    const int tid = threadIdx.x;
    const int lane = tid & 63;
    const int wv = tid >> 6;
    const int l15 = tid & 15;
    const int l16 = (tid >> 4) & 3;
    const int sr = lane >> 5;   // stage row parity (0/1)
    const int sc = lane & 31;   // stage col 0..31
    const int row0 = blockIdx.x * 128 + wv * 32;

    float xr[16];  // in-flight slice: rows 2q+sr, col j*32+sc

    auto issue = [&](int j) {
        const int col = j * 32 + sc;
        const bool ok = col < 125;
#pragma unroll
        for (int q = 0; q < 16; q++) {
            int r = 2 * q + sr;
            xr[q] = ok ? msg[(size_t)(row0 + r) * 125 + col] : 0.f;
        }
    };
    auto writes = [&](int j, int b) {
#pragma unroll
        for (int q = 0; q < 16; q++) {
            int r = 2 * q + sr;
            Xs[wv][b][r * 36 + sc] = xr[q];
        }
    };

    f32x4 acc[8][2];
#pragma unroll
    for (int mt = 0; mt < 8; mt++) {
        f32x4 bi;
#pragma unroll
        for (int r = 0; r < 4; r++) {
            int h_ = mt * 16 + l16 * 4 + r;
            bi[r] = (h_ < HID) ? b1[h_] : 0.f;
        }
        acc[mt][0] = bi;
        acc[mt][1] = bi;
    }

    // ---- pipelined layer 1: issue(j+1) -> MFMA(j) -> write(j+1) ----
    issue(0);
    writes(0, 0);
#pragma unroll
    for (int j = 0; j < 4; ++j) {
        if (j + 1 < 4) issue(j + 1);
        {
            h8 xf[2];
#pragma unroll
            for (int nt = 0; nt < 2; ++nt) {
                const float* rp = &Xs[wv][j & 1][(nt * 16 + l15) * 36 + l16 * 8];
                float t[8];
#pragma unroll
                for (int i = 0; i < 8; i++) t[i] = rp[i];
                v4u xv = {pkh(t[0], t[1]), pkh(t[2], t[3]),
                          pkh(t[4], t[5]), pkh(t[6], t[7])};
                xf[nt] = __builtin_bit_cast(h8, xv);
            }
#pragma unroll
            for (int mt = 0; mt < 8; ++mt) {
                h8 wf = *(const h8*)&w1g[(size_t)((j * 8 + mt) * 64 + lane) * 8];
                acc[mt][0] = __builtin_amdgcn_mfma_f32_16x16x32_f16(wf, xf[0], acc[mt][0], 0, 0, 0);
                acc[mt][1] = __builtin_amdgcn_mfma_f32_16x16x32_f16(wf, xf[1], acc[mt][1], 0, 0, 0);
            }
        }
        if (j + 1 < 4) writes(j + 1, (j + 1) & 1);  // vmcnt wait lands after MFMA
    }

    // ---- lrelu + layer 2 (r11-verbatim) ----
#pragma unroll
    for (int mt = 0; mt < 8; mt++)
#pragma unroll
        for (int nt = 0; nt < 2; nt++)
#pragma unroll
            for (int r = 0; r < 4; r++)
                acc[mt][nt][r] = fmaxf(acc[mt][nt][r], 0.01f * acc[mt][nt][r]);

    float b2v[3];
#pragma unroll
    for (int qt = 0; qt < 3; qt++) {
        int q = qt * 16 + l15;
        b2v[qt] = (q < OUT) ? b2[q] : 0.f;
    }

    unsigned short* s16 = (unsigned short*)&Xs[wv][0][0];  // bounce (buf0 free)
#pragma unroll
    for (int nt = 0; nt < 2; ++nt) {
        h8 A[4];
#pragma unroll
        for (int kt = 0; kt < 4; kt++) {
            v4u av = {pkh(acc[2 * kt][nt][0], acc[2 * kt][nt][1]),
                      pkh(acc[2 * kt][nt][2], acc[2 * kt][nt][3]),
                      pkh(acc[2 * kt + 1][nt][0], acc[2 * kt + 1][nt][1]),
                      pkh(acc[2 * kt + 1][nt][2], acc[2 * kt + 1][nt][3])};
            A[kt] = __builtin_bit_cast(h8, av);
        }
#pragma unroll
        for (int qt = 0; qt < 3; ++qt) {
            f32x4 o = {0.f, 0.f, 0.f, 0.f};
#pragma unroll
            for (int kt = 0; kt < 4; kt++) {
                v4u wvv = ((const v4u*)w2f)[(kt * 3 + qt) * 64 + lane];
                o = __builtin_amdgcn_mfma_f32_16x16x32_f16(
                    A[kt], __builtin_bit_cast(h8, wvv), o, 0, 0, 0);
            }
            int q = qt * 16 + l15;
            if (q < OUT) {
#pragma unroll
                for (int r = 0; r < 4; r++) {
                    int rl = nt * 16 + l16 * 4 + r;  // local row in wave
                    float v = o[r] + b2v[qt];
                    v = fmaxf(v, 0.01f * v);
                    s16[rl * 40 + q] = f2h(v);
                }
            }
        }
    }
    // coalesced store: 32 rows x 40 f16 = 2560 B
    {
        v4u* gdst = (v4u*)(outp + (size_t)row0 * 40);
        const v4u* s4 = (const v4u*)s16;
#pragma unroll
        for (int i = 0; i < 3; i++) {
            int u = lane + i * 64;
            if (i < 2 || u < 160) gdst[u] = s4[u];
        }
    }
}

// ========================= mid/final kernel (r11 verbatim) =========================
// MODE 1: sibling-summed f16 out; MODE 2: sibling-summed fp32 out (final).
template <int MODE>
__global__ void __launch_bounds__(256, 4)
mid_k(const float* __restrict__ msg, const float* __restrict__ bonds,
      const unsigned short* __restrict__ child,
      const unsigned short* __restrict__ w1g, const unsigned int* __restrict__ w2f,
      const float* __restrict__ b1, const float* __restrict__ b2,
      void* __restrict__ outp) {
    __shared__ float MS[4][1000];            // 8 parents x 125 f32
    __shared__ float BS[4][384];             // 32 rows x 12 f32
    __shared__ unsigned short CS[4][1280];   // 32 rows x 40 f16

    const int tid = threadIdx.x;
    const int lane = tid & 63;
    const int wv = tid >> 6;
    const int l15 = tid & 15;
    const int l16 = (tid >> 4) & 3;
    const int row0 = blockIdx.x * 128 + wv * 32;  // edge rows
    const int par0 = row0 >> 2;                   // parent rows

    // ---- stage (all wave-private, contiguous, coalesced) ----
    {
        const f32x4* sm = (const f32x4*)(msg + (size_t)par0 * 125);
        f32x4* dm = (f32x4*)&MS[wv][0];
#pragma unroll
        for (int i = 0; i < 4; i++) {
            int u = lane + i * 64;
            if (i < 3 || u < 250) dm[u] = sm[u];
        }
        const f32x4* sb = (const f32x4*)(bonds + (size_t)row0 * 12);
        f32x4* db = (f32x4*)&BS[wv][0];
#pragma unroll
        for (int i = 0; i < 2; i++) {
            int u = lane + i * 64;
            if (i < 1 || u < 96) db[u] = sb[u];
        }
        const v4u* sc = (const v4u*)(child + (size_t)row0 * 40);
        v4u* dc = (v4u*)&CS[wv][0];
#pragma unroll
        for (int i = 0; i < 3; i++) {
            int u = lane + i * 64;
            if (i < 2 || u < 160) dc[u] = sc[u];
        }
    }

    f32x4 acc[8][2];
#pragma unroll
    for (int mt = 0; mt < 8; mt++) {
        f32x4 bi;
#pragma unroll
        for (int r = 0; r < 4; r++) {
            int h_ = mt * 16 + l16 * 4 + r;
            bi[r] = (h_ < HID) ? b1[h_] : 0.f;
        }
        acc[mt][0] = bi;
        acc[mt][1] = bi;
    }

    // ---- layer 1: 6 chunks ----
#pragma unroll
    for (int j = 0; j < 6; ++j) {
        h8 xf[2];
#pragma unroll
        for (int nt = 0; nt < 2; ++nt) {
            const int rl = nt * 16 + l15;  // local edge row 0..31
            if (j < 4) {
                const float* pp = &MS[wv][(rl >> 2) * 125];
                const int k0 = j * 32 + l16 * 8;
                float t[8];
#pragma unroll
                for (int i = 0; i < 8; i++) {
                    int col = k0 + i;
                    int cs = (col < 125) ? col : 0;
                    float v = pp[cs];
                    t[i] = (col < 125) ? v : 0.f;
                }
                v4u xv = {pkh(t[0], t[1]), pkh(t[2], t[3]), pkh(t[4], t[5]), pkh(t[6], t[7])};
                xf[nt] = __builtin_bit_cast(h8, xv);
            } else if (j == 4) {
                if (l16 < 2) {
                    const float* bp = &BS[wv][rl * 12];
                    float t[8];
#pragma unroll
                    for (int i = 0; i < 8; i++) {
                        int c = l16 * 8 + i;
                        int cs = (c < 12) ? c : 0;
                        float v = bp[cs];
                        t[i] = (c < 12) ? v : 0.f;
                    }
                    v4u xv = {pkh(t[0], t[1]), pkh(t[2], t[3]), pkh(t[4], t[5]), pkh(t[6], t[7])};
                    xf[nt] = __builtin_bit_cast(h8, xv);
                } else {
                    xf[nt] = *(const h8*)&CS[wv][rl * 40 + (l16 - 2) * 8];  // child 0..15
                }
            } else {
                if (l16 < 3) {
                    xf[nt] = *(const h8*)&CS[wv][rl * 40 + 16 + l16 * 8];   // child 16..39
                } else {
                    h8 z = {};
                    xf[nt] = z;
                }
            }
        }
#pragma unroll
        for (int mt = 0; mt < 8; ++mt) {
            h8 wf = *(const h8*)&w1g[(size_t)((j * 8 + mt) * 64 + lane) * 8];
            acc[mt][0] = __builtin_amdgcn_mfma_f32_16x16x32_f16(wf, xf[0], acc[mt][0], 0, 0, 0);
            acc[mt][1] = __builtin_amdgcn_mfma_f32_16x16x32_f16(wf, xf[1], acc[mt][1], 0, 0, 0);
        }
    }

    // ---- lrelu + layer 2 + sibling sum ----
#pragma unroll
    for (int mt = 0; mt < 8; mt++)
#pragma unroll
        for (int nt = 0; nt < 2; nt++)
#pragma unroll
            for (int r = 0; r < 4; r++)
                acc[mt][nt][r] = fmaxf(acc[mt][nt][r], 0.01f * acc[mt][nt][r]);

    float b2v[3];
#pragma unroll
    for (int qt = 0; qt < 3; qt++) {
        int q = qt * 16 + l15;
        b2v[qt] = (q < OUT) ? b2[q] : 0.f;
    }
#pragma unroll
    for (int nt = 0; nt < 2; ++nt) {
        h8 A[4];
#pragma unroll
        for (int kt = 0; kt < 4; kt++) {
            v4u av = {pkh(acc[2 * kt][nt][0], acc[2 * kt][nt][1]),
                      pkh(acc[2 * kt][nt][2], acc[2 * kt][nt][3]),
                      pkh(acc[2 * kt + 1][nt][0], acc[2 * kt + 1][nt][1]),
                      pkh(acc[2 * kt + 1][nt][2], acc[2 * kt + 1][nt][3])};
            A[kt] = __builtin_bit_cast(h8, av);
        }
#pragma unroll
        for (int qt = 0; qt < 3; ++qt) {
            f32x4 o = {0.f, 0.f, 0.f, 0.f};
#pragma unroll
            for (int kt = 0; kt < 4; kt++) {
                v4u wvv = ((const v4u*)w2f)[(kt * 3 + qt) * 64 + lane];
                o = __builtin_amdgcn_mfma_f32_16x16x32_f16(
                    A[kt], __builtin_bit_cast(h8, wvv), o, 0, 0, 0);
            }
            int q = qt * 16 + l15;
            float s = 0.f;
#pragma unroll
            for (int r = 0; r < 4; r++) {
                float v = o[r] + b2v[qt];
                s += fmaxf(v, 0.01f * v);
            }
            if (q < OUT) {
                int p = par0 + (nt * 16 + l16 * 4) / 4;  // = par0 + nt*4 + l16
                if (MODE == 1)
                    ((unsigned short*)outp)[(size_t)p * 40 + q] = f2h(s);
                else
                    ((float*)outp)[(size_t)p * 40 + q] = s;
            }
        }
    }
}

extern "C" void kernel_launch(void* const* d_in, const int* in_sizes, int n_in,
                              void* d_out, int out_size, void* d_ws, size_t ws_size,
                              hipStream_t stream) {
    const float* node_msg = (const float*)d_in[0];
    const float* bonds = (const float*)d_in[1];
    const float* W1 = (const float*)d_in[2];
    const float* b1 = (const float*)d_in[3];
    const float* W2 = (const float*)d_in[4];
    const float* b2 = (const float*)d_in[5];
    float* out = (float*)d_out;

    char* ws = (char*)d_ws;
    unsigned short* bufA = (unsigned short*)ws;                   // 524288*40 f16
    unsigned short* bufB = (unsigned short*)(ws + 41943040);      // 131072*40 f16
    unsigned short* w1g = (unsigned short*)(ws + 52428800);       // 49152 B
    unsigned int* w2f = (unsigned int*)(ws + 52428800 + 49152);   // 12288 B

    prep_w1g<<<96, 256, 0, stream>>>(W1, w1g);
    prep_w2<<<1, 256, 0, stream>>>(W2, w2f);

    // leaf (d=4): 524288 rows -> bufA
    leaf_k<<<4096, 256, 0, stream>>>(
        node_msg + (size_t)175104 * 125, w1g, w2f, b1, b2, bufA);
    // d=3: 524288 edges -> 131072 parents -> bufB
    mid_k<1><<<4096, 256, 0, stream>>>(
        node_msg + (size_t)43008 * 125, bonds + (size_t)172032 * 12, bufA,
        w1g, w2f, b1, b2, bufB);
    // d=2: 131072 edges -> 32768 parents -> bufA
    mid_k<1><<<1024, 256, 0, stream>>>(
        node_msg + (size_t)10240 * 125, bonds + (size_t)40960 * 12, bufB,
        w1g, w2f, b1, b2, bufA);
    // d=1: 32768 edges -> 8192 parents -> bufB
    mid_k<1><<<256, 256, 0, stream>>>(
        node_msg + (size_t)2048 * 125, bonds + (size_t)8192 * 12, bufA,
        w1g, w2f, b1, b2, bufB);
    // d=0: 8192 edges -> 2048 parents -> out (fp32)
    mid_k<2><<<64, 256, 0, stream>>>(
        node_msg, bonds, bufB, w1g, w2f, b1, b2, out);
}

// Round 14
// 194.604 us; speedup vs baseline: 1.2345x; 1.0413x over previous
//
#include <hip/hip_runtime.h>
#include <hip/hip_bf16.h>
#include <cstddef>

// K=2048, B=4, D=5, ATOM=125, BOND=12, HID=125, OUT=40
// NOFF = [0, 2048, 10240, 43008, 175104, 699392]
// BOFF = [0, 8192, 40960, 172032, 696320]
//
// Round 14 = round 13 with:
//  - leaf: DEPTH-2 chunk prefetch (two reg sets, explicit unrolled schedule;
//    counted vmcnt keeps 2 chunks of loads in flight across the ds_writes)
//  - prep_w1g + prep_w2 merged into one kernel (one fewer dispatch)
//  - mid_k and all fragment mappings: r13 VERBATIM
// k' layout (192): [0,125) msg, [125,128) 0, [128,140) bond, [140,144) 0,
// [144,184) child, [184,192) 0. f16, RNE. Intermediates [row][40] f16.

typedef __attribute__((ext_vector_type(8))) _Float16 h8;
typedef __attribute__((ext_vector_type(4))) float f32x4;
typedef __attribute__((ext_vector_type(4))) unsigned int v4u;

static constexpr int HID = 125, OUT = 40;

__device__ __forceinline__ unsigned short f2h(float x) {
    _Float16 h = (_Float16)x;  // RNE
    return __builtin_bit_cast(unsigned short, h);
}
__device__ __forceinline__ unsigned int pkh(float a, float b) {
    return (unsigned int)f2h(a) | ((unsigned int)f2h(b) << 16);
}

// Merged prep: blocks 0..95 build w1g (per-fragment-contiguous W1),
// block 96 builds w2f (frag-packed W2). Mappings validated r3..r13.
__global__ void prep_w(const float* __restrict__ W1, const float* __restrict__ W2,
                       unsigned short* __restrict__ w1g, unsigned int* __restrict__ w2f) {
    if (blockIdx.x < 96) {
        int idx = blockIdx.x * 256 + threadIdx.x;  // < 6*8*64*8 = 24576
        int j = idx & 7, ln = (idx >> 3) & 63, mt = (idx >> 9) & 7, kc = idx >> 12;
        int hid = mt * 16 + (ln & 15);
        int kp = kc * 32 + ((ln >> 4) << 3) + j;
        int k = (kp < 125) ? kp
              : (kp >= 128 && kp < 140) ? kp - 3
              : (kp >= 144 && kp < 184) ? kp - 7 : -1;
        float v = (k >= 0 && hid < HID) ? W1[(size_t)k * HID + hid] : 0.f;
        w1g[idx] = f2h(v);
    } else {
        int t = threadIdx.x;
        for (int task = t; task < 12 * 64; task += 256) {
            int ln = task & 63, fr = task >> 6;
            int kt = fr / 3, qt = fr % 3;
            int q = qt * 16 + (ln & 15);
            unsigned int w[4];
#pragma unroll
            for (int jp = 0; jp < 4; jp++) {
                unsigned short e[2];
#pragma unroll
                for (int s = 0; s < 2; s++) {
                    int j = jp * 2 + s;
                    int hid = kt * 32 + ((j >> 2) << 4) + ((ln >> 4) << 2) + (j & 3);
                    float v = (hid < HID && q < OUT) ? W2[(size_t)hid * OUT + q] : 0.f;
                    e[s] = f2h(v);
                }
                w[jp] = (unsigned int)e[0] | ((unsigned int)e[1] << 16);
            }
            v4u val = {w[0], w[1], w[2], w[3]};
            ((v4u*)w2f)[fr * 64 + ln] = val;
        }
    }
}

// ========================= leaf kernel (d=4) =========================
// 128 rows/block, 32 rows/wave, column-slice staging, DEPTH-2 prefetch.
__global__ void __launch_bounds__(256, 3)
leaf_k(const float* __restrict__ msg, const unsigned short* __restrict__ w1g,
       const unsigned int* __restrict__ w2f,
       const float* __restrict__ b1, const float* __restrict__ b2,
       unsigned short* __restrict__ outp) {
    __shared__ float Xs[4][2][32 * 36];  // per-wave dbuf slice: 32 rows x 36 f32

    const int tid = threadIdx.x;
    const int lane = tid & 63;
    const int wv = tid >> 6;
    const int l15 = tid & 15;
    const int l16 = (tid >> 4) & 3;
    const int sr = lane >> 5;   // stage row parity (0/1)
    const int sc = lane & 31;   // stage col 0..31
    const int row0 = blockIdx.x * 128 + wv * 32;

    float xa[16], xb[16];  // two in-flight slice register sets

    auto issueA = [&](int j) {
        const int col = j * 32 + sc;
        const bool ok = col < 125;
#pragma unroll
        for (int q = 0; q < 16; q++)
            xa[q] = ok ? msg[(size_t)(row0 + 2 * q + sr) * 125 + col] : 0.f;
    };
    auto issueB = [&](int j) {
        const int col = j * 32 + sc;
        const bool ok = col < 125;
#pragma unroll
        for (int q = 0; q < 16; q++)
            xb[q] = ok ? msg[(size_t)(row0 + 2 * q + sr) * 125 + col] : 0.f;
    };
    auto writeA = [&](int b) {
#pragma unroll
        for (int q = 0; q < 16; q++) Xs[wv][b][(2 * q + sr) * 36 + sc] = xa[q];
    };
    auto writeB = [&](int b) {
#pragma unroll
        for (int q = 0; q < 16; q++) Xs[wv][b][(2 * q + sr) * 36 + sc] = xb[q];
    };

    f32x4 acc[8][2];
#pragma unroll
    for (int mt = 0; mt < 8; mt++) {
        f32x4 bi;
#pragma unroll
        for (int r = 0; r < 4; r++) {
            int h_ = mt * 16 + l16 * 4 + r;
            bi[r] = (h_ < HID) ? b1[h_] : 0.f;
        }
        acc[mt][0] = bi;
        acc[mt][1] = bi;
    }

    auto mfma_chunk = [&](int j, int b) {
        h8 xf[2];
#pragma unroll
        for (int nt = 0; nt < 2; ++nt) {
            const float* rp = &Xs[wv][b][(nt * 16 + l15) * 36 + l16 * 8];
            float t[8];
#pragma unroll
            for (int i = 0; i < 8; i++) t[i] = rp[i];
            v4u xv = {pkh(t[0], t[1]), pkh(t[2], t[3]),
                      pkh(t[4], t[5]), pkh(t[6], t[7])};
            xf[nt] = __builtin_bit_cast(h8, xv);
        }
#pragma unroll
        for (int mt = 0; mt < 8; ++mt) {
            h8 wf = *(const h8*)&w1g[(size_t)((j * 8 + mt) * 64 + lane) * 8];
            acc[mt][0] = __builtin_amdgcn_mfma_f32_16x16x32_f16(wf, xf[0], acc[mt][0], 0, 0, 0);
            acc[mt][1] = __builtin_amdgcn_mfma_f32_16x16x32_f16(wf, xf[1], acc[mt][1], 0, 0, 0);
        }
    };

    // ---- depth-2 pipelined layer 1 (explicit schedule, NC=4) ----
    issueA(0);
    writeA(0);      // prologue drain (A only)
    issueB(1);
    issueA(2);      // 2nd prefetch in flight
    mfma_chunk(0, 0);
    writeB(1);      // counted vmcnt: waits B, leaves A(2) outstanding
    issueB(3);
    mfma_chunk(1, 1);
    writeA(0);      // waits A(2), leaves B(3) outstanding
    mfma_chunk(2, 0);
    writeB(1);      // waits B(3)
    mfma_chunk(3, 1);

    // ---- lrelu + layer 2 ----
#pragma unroll
    for (int mt = 0; mt < 8; mt++)
#pragma unroll
        for (int nt = 0; nt < 2; nt++)
#pragma unroll
            for (int r = 0; r < 4; r++)
                acc[mt][nt][r] = fmaxf(acc[mt][nt][r], 0.01f * acc[mt][nt][r]);

    float b2v[3];
#pragma unroll
    for (int qt = 0; qt < 3; qt++) {
        int q = qt * 16 + l15;
        b2v[qt] = (q < OUT) ? b2[q] : 0.f;
    }

    unsigned short* s16 = (unsigned short*)&Xs[wv][0][0];  // bounce (buf0 free)
#pragma unroll
    for (int nt = 0; nt < 2; ++nt) {
        h8 A[4];
#pragma unroll
        for (int kt = 0; kt < 4; kt++) {
            v4u av = {pkh(acc[2 * kt][nt][0], acc[2 * kt][nt][1]),
                      pkh(acc[2 * kt][nt][2], acc[2 * kt][nt][3]),
                      pkh(acc[2 * kt + 1][nt][0], acc[2 * kt + 1][nt][1]),
                      pkh(acc[2 * kt + 1][nt][2], acc[2 * kt + 1][nt][3])};
            A[kt] = __builtin_bit_cast(h8, av);
        }
#pragma unroll
        for (int qt = 0; qt < 3; ++qt) {
            f32x4 o = {0.f, 0.f, 0.f, 0.f};
#pragma unroll
            for (int kt = 0; kt < 4; kt++) {
                v4u wvv = ((const v4u*)w2f)[(kt * 3 + qt) * 64 + lane];
                o = __builtin_amdgcn_mfma_f32_16x16x32_f16(
                    A[kt], __builtin_bit_cast(h8, wvv), o, 0, 0, 0);
            }
            int q = qt * 16 + l15;
            if (q < OUT) {
#pragma unroll
                for (int r = 0; r < 4; r++) {
                    int rl = nt * 16 + l16 * 4 + r;  // local row in wave
                    float v = o[r] + b2v[qt];
                    v = fmaxf(v, 0.01f * v);
                    s16[rl * 40 + q] = f2h(v);
                }
            }
        }
    }
    // coalesced store: 32 rows x 40 f16 = 2560 B
    {
        v4u* gdst = (v4u*)(outp + (size_t)row0 * 40);
        const v4u* s4 = (const v4u*)s16;
#pragma unroll
        for (int i = 0; i < 3; i++) {
            int u = lane + i * 64;
            if (i < 2 || u < 160) gdst[u] = s4[u];
        }
    }
}

// ========================= mid/final kernel (r13 verbatim) =========================
// MODE 1: sibling-summed f16 out; MODE 2: sibling-summed fp32 out (final).
template <int MODE>
__global__ void __launch_bounds__(256, 4)
mid_k(const float* __restrict__ msg, const float* __restrict__ bonds,
      const unsigned short* __restrict__ child,
      const unsigned short* __restrict__ w1g, const unsigned int* __restrict__ w2f,
      const float* __restrict__ b1, const float* __restrict__ b2,
      void* __restrict__ outp) {
    __shared__ float MS[4][1000];            // 8 parents x 125 f32
    __shared__ float BS[4][384];             // 32 rows x 12 f32
    __shared__ unsigned short CS[4][1280];   // 32 rows x 40 f16

    const int tid = threadIdx.x;
    const int lane = tid & 63;
    const int wv = tid >> 6;
    const int l15 = tid & 15;
    const int l16 = (tid >> 4) & 3;
    const int row0 = blockIdx.x * 128 + wv * 32;  // edge rows
    const int par0 = row0 >> 2;                   // parent rows

    // ---- stage (all wave-private, contiguous, coalesced) ----
    {
        const f32x4* sm = (const f32x4*)(msg + (size_t)par0 * 125);
        f32x4* dm = (f32x4*)&MS[wv][0];
#pragma unroll
        for (int i = 0; i < 4; i++) {
            int u = lane + i * 64;
            if (i < 3 || u < 250) dm[u] = sm[u];
        }
        const f32x4* sb = (const f32x4*)(bonds + (size_t)row0 * 12);
        f32x4* db = (f32x4*)&BS[wv][0];
#pragma unroll
        for (int i = 0; i < 2; i++) {
            int u = lane + i * 64;
            if (i < 1 || u < 96) db[u] = sb[u];
        }
        const v4u* sc = (const v4u*)(child + (size_t)row0 * 40);
        v4u* dc = (v4u*)&CS[wv][0];
#pragma unroll
        for (int i = 0; i < 3; i++) {
            int u = lane + i * 64;
            if (i < 2 || u < 160) dc[u] = sc[u];
        }
    }

    f32x4 acc[8][2];
#pragma unroll
    for (int mt = 0; mt < 8; mt++) {
        f32x4 bi;
#pragma unroll
        for (int r = 0; r < 4; r++) {
            int h_ = mt * 16 + l16 * 4 + r;
            bi[r] = (h_ < HID) ? b1[h_] : 0.f;
        }
        acc[mt][0] = bi;
        acc[mt][1] = bi;
    }

    // ---- layer 1: 6 chunks ----
#pragma unroll
    for (int j = 0; j < 6; ++j) {
        h8 xf[2];
#pragma unroll
        for (int nt = 0; nt < 2; ++nt) {
            const int rl = nt * 16 + l15;  // local edge row 0..31
            if (j < 4) {
                const float* pp = &MS[wv][(rl >> 2) * 125];
                const int k0 = j * 32 + l16 * 8;
                float t[8];
#pragma unroll
                for (int i = 0; i < 8; i++) {
                    int col = k0 + i;
                    int cs = (col < 125) ? col : 0;
                    float v = pp[cs];
                    t[i] = (col < 125) ? v : 0.f;
                }
                v4u xv = {pkh(t[0], t[1]), pkh(t[2], t[3]), pkh(t[4], t[5]), pkh(t[6], t[7])};
                xf[nt] = __builtin_bit_cast(h8, xv);
            } else if (j == 4) {
                if (l16 < 2) {
                    const float* bp = &BS[wv][rl * 12];
                    float t[8];
#pragma unroll
                    for (int i = 0; i < 8; i++) {
                        int c = l16 * 8 + i;
                        int cs = (c < 12) ? c : 0;
                        float v = bp[cs];
                        t[i] = (c < 12) ? v : 0.f;
                    }
                    v4u xv = {pkh(t[0], t[1]), pkh(t[2], t[3]), pkh(t[4], t[5]), pkh(t[6], t[7])};
                    xf[nt] = __builtin_bit_cast(h8, xv);
                } else {
                    xf[nt] = *(const h8*)&CS[wv][rl * 40 + (l16 - 2) * 8];  // child 0..15
                }
            } else {
                if (l16 < 3) {
                    xf[nt] = *(const h8*)&CS[wv][rl * 40 + 16 + l16 * 8];   // child 16..39
                } else {
                    h8 z = {};
                    xf[nt] = z;
                }
            }
        }
#pragma unroll
        for (int mt = 0; mt < 8; ++mt) {
            h8 wf = *(const h8*)&w1g[(size_t)((j * 8 + mt) * 64 + lane) * 8];
            acc[mt][0] = __builtin_amdgcn_mfma_f32_16x16x32_f16(wf, xf[0], acc[mt][0], 0, 0, 0);
            acc[mt][1] = __builtin_amdgcn_mfma_f32_16x16x32_f16(wf, xf[1], acc[mt][1], 0, 0, 0);
        }
    }

    // ---- lrelu + layer 2 + sibling sum ----
#pragma unroll
    for (int mt = 0; mt < 8; mt++)
#pragma unroll
        for (int nt = 0; nt < 2; nt++)
#pragma unroll
            for (int r = 0; r < 4; r++)
                acc[mt][nt][r] = fmaxf(acc[mt][nt][r], 0.01f * acc[mt][nt][r]);

    float b2v[3];
#pragma unroll
    for (int qt = 0; qt < 3; qt++) {
        int q = qt * 16 + l15;
        b2v[qt] = (q < OUT) ? b2[q] : 0.f;
    }
#pragma unroll
    for (int nt = 0; nt < 2; ++nt) {
        h8 A[4];
#pragma unroll
        for (int kt = 0; kt < 4; kt++) {
            v4u av = {pkh(acc[2 * kt][nt][0], acc[2 * kt][nt][1]),
                      pkh(acc[2 * kt][nt][2], acc[2 * kt][nt][3]),
                      pkh(acc[2 * kt + 1][nt][0], acc[2 * kt + 1][nt][1]),
                      pkh(acc[2 * kt + 1][nt][2], acc[2 * kt + 1][nt][3])};
            A[kt] = __builtin_bit_cast(h8, av);
        }
#pragma unroll
        for (int qt = 0; qt < 3; ++qt) {
            f32x4 o = {0.f, 0.f, 0.f, 0.f};
#pragma unroll
            for (int kt = 0; kt < 4; kt++) {
                v4u wvv = ((const v4u*)w2f)[(kt * 3 + qt) * 64 + lane];
                o = __builtin_amdgcn_mfma_f32_16x16x32_f16(
                    A[kt], __builtin_bit_cast(h8, wvv), o, 0, 0, 0);
            }
            int q = qt * 16 + l15;
            float s = 0.f;
#pragma unroll
            for (int r = 0; r < 4; r++) {
                float v = o[r] + b2v[qt];
                s += fmaxf(v, 0.01f * v);
            }
            if (q < OUT) {
                int p = par0 + nt * 4 + l16;
                if (MODE == 1)
                    ((unsigned short*)outp)[(size_t)p * 40 + q] = f2h(s);
                else
                    ((float*)outp)[(size_t)p * 40 + q] = s;
            }
        }
    }
}

extern "C" void kernel_launch(void* const* d_in, const int* in_sizes, int n_in,
                              void* d_out, int out_size, void* d_ws, size_t ws_size,
                              hipStream_t stream) {
    const float* node_msg = (const float*)d_in[0];
    const float* bonds = (const float*)d_in[1];
    const float* W1 = (const float*)d_in[2];
    const float* b1 = (const float*)d_in[3];
    const float* W2 = (const float*)d_in[4];
    const float* b2 = (const float*)d_in[5];
    float* out = (float*)d_out;

    char* ws = (char*)d_ws;
    unsigned short* bufA = (unsigned short*)ws;                   // 524288*40 f16
    unsigned short* bufB = (unsigned short*)(ws + 41943040);      // 131072*40 f16
    unsigned short* w1g = (unsigned short*)(ws + 52428800);       // 49152 B
    unsigned int* w2f = (unsigned int*)(ws + 52428800 + 49152);   // 12288 B

    prep_w<<<97, 256, 0, stream>>>(W1, W2, w1g, w2f);

    // leaf (d=4): 524288 rows -> bufA
    leaf_k<<<4096, 256, 0, stream>>>(
        node_msg + (size_t)175104 * 125, w1g, w2f, b1, b2, bufA);
    // d=3: 524288 edges -> 131072 parents -> bufB
    mid_k<1><<<4096, 256, 0, stream>>>(
        node_msg + (size_t)43008 * 125, bonds + (size_t)172032 * 12, bufA,
        w1g, w2f, b1, b2, bufB);
    // d=2: 131072 edges -> 32768 parents -> bufA
    mid_k<1><<<1024, 256, 0, stream>>>(
        node_msg + (size_t)10240 * 125, bonds + (size_t)40960 * 12, bufB,
        w1g, w2f, b1, b2, bufA);
    // d=1: 32768 edges -> 8192 parents -> bufB
    mid_k<1><<<256, 256, 0, stream>>>(
        node_msg + (size_t)2048 * 125, bonds + (size_t)8192 * 12, bufA,
        w1g, w2f, b1, b2, bufB);
    // d=0: 8192 edges -> 2048 parents -> out (fp32)
    mid_k<2><<<64, 256, 0, stream>>>(
        node_msg, bonds, bufB, w1g, w2f, b1, b2, out);
}